// Round 2
// baseline (463.424 us; speedup 1.0000x reference)
//
#include <hip/hip_runtime.h>
#include <cstddef>

// Problem constants (from reference)
constexpr int TTOT  = 65536;
constexpr int CHANS = 64;
constexpr int WLEN  = 25;
constexpr int ETAS  = 25;
constexpr int LOUT  = TTOT - WLEN + 1;       // 65512
constexpr int LT    = 52;                    // l-tile per block (13 iters x 4 lsubs)
constexpr int ROWS  = LT + WLEN - 1;         // 76 staged input rows
constexpr int NBLK  = (LOUT + LT - 1) / LT;  // 1260 blocks

// Kernel 1: build the 25x25 wavelet table in workspace.
// win[e][k] = exp(-a[e]^2 t^2 / 2) * cos(2*pi*b[e]*t), t = (k-12)*0.03
// (window is even in t, so the reference's [::-1] flip is identity)
__global__ void win_kernel(const float* __restrict__ a,
                           const float* __restrict__ b,
                           float* __restrict__ win) {
    int idx = blockIdx.x * blockDim.x + threadIdx.x;
    if (idx >= ETAS * WLEN) return;
    int e = idx / WLEN;
    int k = idx - e * WLEN;
    float t  = (float)(k - 12) * 0.03f;
    float ae = a[e];
    float be = b[e];
    float g  = expf(-0.5f * ae * ae * t * t);
    float c  = cosf(6.28318530717958647692f * be * t);
    win[idx] = g * c;
}

// Kernel 2: depthwise 25-tap conv, out[l,e,c] = sum_k in[l+k,c]*win[e,k]
// Block: 256 threads = 64 channels x 4 l-sublanes. LDS-staged input tile.
__global__ __launch_bounds__(256) void conv_kernel(
    const float* __restrict__ in,
    const float* __restrict__ win,
    float* __restrict__ out) {
    __shared__ float xs[ROWS * CHANS];          // 76*64*4 = 19456 B

    const int l0 = blockIdx.x * LT;

    // --- stage input rows [l0, l0+ROWS) into LDS, float4-coalesced ---
    {
        const float4* in4 = reinterpret_cast<const float4*>(in + (size_t)l0 * CHANS);
        float4* xs4 = reinterpret_cast<float4*>(xs);
        constexpr int N4 = (ROWS * CHANS) / 4;  // 1216
        for (int i4 = threadIdx.x; i4 < N4; i4 += 256) {
            int r = i4 >> 4;                    // row = (i4*4)/64
            float4 v = make_float4(0.f, 0.f, 0.f, 0.f);
            if (l0 + r < TTOT) v = in4[i4];     // tail-block guard
            xs4[i4] = v;
        }
    }
    __syncthreads();

    const int c  = threadIdx.x & 63;
    const int ls = threadIdx.x >> 6;            // 0..3 (wave-uniform)

    for (int li = ls; li < LT; li += 4) {
        const int l = l0 + li;
        if (l >= LOUT) break;                   // wave-uniform branch

        // 25 input taps for this (l, c) into registers
        float x[WLEN];
#pragma unroll
        for (int k = 0; k < WLEN; ++k)
            x[k] = xs[(li + k) * CHANS + c];

        const size_t obase = (size_t)l * (ETAS * CHANS) + c;
        for (int e = 0; e < ETAS; ++e) {
            const float* w = win + e * WLEN;    // wave-uniform -> scalar loads
            float acc = 0.f;
#pragma unroll
            for (int k = 0; k < WLEN; ++k)
                acc = fmaf(x[k], w[k], acc);
            out[obase + (size_t)(e * CHANS)] = acc;
        }
    }
}

extern "C" void kernel_launch(void* const* d_in, const int* in_sizes, int n_in,
                              void* d_out, int out_size, void* d_ws, size_t ws_size,
                              hipStream_t stream) {
    const float* in = (const float*)d_in[0];   // (65536, 64)
    const float* a  = (const float*)d_in[1];   // (25,)
    const float* b  = (const float*)d_in[2];   // (25,)
    float* out = (float*)d_out;                // (65512, 25, 64)
    float* win = (float*)d_ws;                 // 625 floats of scratch

    win_kernel<<<(ETAS * WLEN + 255) / 256, 256, 0, stream>>>(a, b, win);
    conv_kernel<<<NBLK, 256, 0, stream>>>(in, win, out);
}

// Round 4
// 448.890 us; speedup vs baseline: 1.0324x; 1.0324x over previous
//
#include <hip/hip_runtime.h>
#include <cstddef>

// Problem constants (from reference)
constexpr int TTOT  = 65536;
constexpr int CHANS = 64;
constexpr int WLEN  = 25;
constexpr int ETAS  = 25;
constexpr int LOUT  = TTOT - WLEN + 1;          // 65512
constexpr int LPW   = 13;                       // output rows per wave
constexpr int TAPS  = LPW + WLEN - 1;           // 37 register-resident taps
constexpr int WPB   = 4;                        // waves per block (256 thr)
constexpr int NTILE = (LOUT + LPW - 1) / LPW;   // 5040 wave-tiles
constexpr int NBLK  = (NTILE + WPB - 1) / WPB;  // 1260 blocks

// Kernel 1: 25x25 wavelet table into workspace (recomputed every launch —
// d_ws is re-poisoned by the harness before each timed call).
// win[e][k] = exp(-a[e]^2 t^2/2) * cos(2*pi*b[e]*t), t=(k-12)*0.03.
// Window is even in t so the reference's [::-1] flip is identity.
__global__ void win_kernel(const float* __restrict__ a,
                           const float* __restrict__ b,
                           float* __restrict__ win) {
    int idx = blockIdx.x * blockDim.x + threadIdx.x;
    if (idx >= ETAS * WLEN) return;
    int e = idx / WLEN;
    int k = idx - e * WLEN;
    float t  = (float)(k - 12) * 0.03f;
    float ae = a[e];
    float be = b[e];
    float g  = expf(-0.5f * ae * ae * t * t);
    float c  = cosf(6.28318530717958647692f * be * t);
    win[idx] = g * c;
}

// Kernel 2: out[l,e,c] = sum_k in[l+k,c] * win[e,k]
// One wave owns 13 consecutive l's for all 64 channels (lane = c).
// 37-tap input window lives in registers; win coeffs are wave-uniform
// scalar loads (1 SGPR operand per v_fma). No LDS, no barriers.
__global__ __launch_bounds__(256) void conv_kernel(
    const float* __restrict__ in,
    const float* __restrict__ win,
    float* __restrict__ out) {
    const int c    = threadIdx.x & 63;
    const int wv   = threadIdx.x >> 6;                 // wave id in block
    const int tile = blockIdx.x * WPB + wv;
    const int lBase = tile * LPW;
    if (lBase >= LOUT) return;                         // wave-uniform

    // --- 37 input taps -> registers (coalesced 256B per row) ---
    // Rows past TTOT-1 are clamped: they only feed l >= LOUT, whose
    // stores are guarded out below.
    float x[TAPS];
#pragma unroll
    for (int r = 0; r < TAPS; ++r) {
        int row = lBase + r;
        if (row > TTOT - 1) row = TTOT - 1;
        x[r] = in[(size_t)row * CHANS + c];
    }

    const int lrem = LOUT - lBase;                     // valid l's this wave

#pragma unroll 1
    for (int e = 0; e < ETAS; ++e) {
        // 25 wave-uniform wavelet coeffs (scalar loads / SGPRs)
        float w[WLEN];
#pragma unroll
        for (int k = 0; k < WLEN; ++k) w[k] = win[e * WLEN + k];

        float* op = out + (size_t)lBase * (ETAS * CHANS) + e * CHANS + c;
#pragma unroll
        for (int j = 0; j < LPW; ++j) {
            float acc = 0.f;
#pragma unroll
            for (int k = 0; k < WLEN; ++k)
                acc = fmaf(x[j + k], w[k], acc);
            if (j < lrem)                              // wave-uniform guard
                op[(size_t)j * (ETAS * CHANS)] = acc;
        }
    }
}

extern "C" void kernel_launch(void* const* d_in, const int* in_sizes, int n_in,
                              void* d_out, int out_size, void* d_ws, size_t ws_size,
                              hipStream_t stream) {
    const float* in = (const float*)d_in[0];   // (65536, 64)
    const float* a  = (const float*)d_in[1];   // (25,)
    const float* b  = (const float*)d_in[2];   // (25,)
    float* out = (float*)d_out;                // (65512, 25, 64)
    float* win = (float*)d_ws;                 // 625 floats of scratch

    win_kernel<<<(ETAS * WLEN + 255) / 256, 256, 0, stream>>>(a, b, win);
    conv_kernel<<<NBLK, 256, 0, stream>>>(in, win, out);
}